// Round 1
// 628.153 us; speedup vs baseline: 1.0042x; 1.0042x over previous
//
#include <hip/hip_runtime.h>
#include <math.h>

static constexpr int B  = 4;
static constexpr int S  = 2048;
static constexpr int D  = 1024;
static constexpr int H  = 16;
static constexpr int DFF = 4096;

typedef __attribute__((ext_vector_type(8))) short short8;
typedef __attribute__((ext_vector_type(8))) unsigned short ushort8;
typedef __attribute__((ext_vector_type(4))) unsigned short ushort4v;
typedef __attribute__((ext_vector_type(4))) float f32x4;

__device__ __forceinline__ float b2f(unsigned short u) {
  unsigned int x = ((unsigned int)u) << 16;
  float f;
  __builtin_memcpy(&f, &x, 4);
  return f;
}
__device__ __forceinline__ unsigned short f2b(float f) {
  unsigned int x;
  __builtin_memcpy(&x, &f, 4);
  x += 0x7fffu + ((x >> 16) & 1u);  // round-to-nearest-even
  return (unsigned short)(x >> 16);
}

__device__ __forceinline__ f32x4 mfma16(short8 a, short8 b, f32x4 c) {
  return __builtin_amdgcn_mfma_f32_16x16x32_bf16(a, b, c, 0, 0, 0);
}

// global -> LDS direct copy, 16B per lane (wave-uniform base + lane*16).
__device__ __forceinline__ void gload_lds16(const void* gsrc, void* ldst) {
  __builtin_amdgcn_global_load_lds(
      (__attribute__((address_space(1))) void*)(uintptr_t)gsrc,
      (__attribute__((address_space(3))) void*)ldst, 16, 0, 0);
}

#define LGK0 asm volatile("s_waitcnt lgkmcnt(0)" ::: "memory")
#define VMC8 asm volatile("s_waitcnt vmcnt(8)" ::: "memory")
#define VMC0 asm volatile("s_waitcnt vmcnt(0)" ::: "memory")
#define SB0  __builtin_amdgcn_sched_barrier(0)
#define BAR  __builtin_amdgcn_s_barrier()
#define PRIO1 __builtin_amdgcn_s_setprio(1)
#define PRIO0 __builtin_amdgcn_s_setprio(0)

// ---------------------------------------------------------------------------
// Batched f32 -> bf16 convert: 6 segments, grid (maxblocks, 6)
// ---------------------------------------------------------------------------
struct CvtArgs {
  const float* s[6];
  unsigned short* d[6];
  int n[6];
};
__global__ __launch_bounds__(256) void convert6(CvtArgs a) {
  const int seg = blockIdx.y;
  const int i = (blockIdx.x * 256 + threadIdx.x) * 4;
  if (i < a.n[seg]) {
    f32x4 v = *(const f32x4*)(a.s[seg] + i);
    ushort4v o;
#pragma unroll
    for (int j = 0; j < 4; j++) o[j] = f2b(v[j]);
    *(ushort4v*)(a.d[seg] + i) = o;
  }
}

// ---------------------------------------------------------------------------
// Fused LayerNorm (f32 in -> bf16 out): alpha*(x-mean)/(std+eps)+beta, ddof=1
// ---------------------------------------------------------------------------
__global__ __launch_bounds__(256) void ln_fused(const float* __restrict__ x,
                                                const float* __restrict__ ap,
                                                const float* __restrict__ cp,
                                                unsigned short* __restrict__ out) {
  const int row = blockIdx.x, tid = threadIdx.x;
  const size_t base = (size_t)row * D;
  float v[4];
  float s = 0.f, sq = 0.f;
#pragma unroll
  for (int i = 0; i < 4; i++) {
    v[i] = x[base + tid + i * 256];
    s += v[i];
    sq += v[i] * v[i];
  }
#pragma unroll
  for (int o = 32; o > 0; o >>= 1) {
    s += __shfl_xor(s, o);
    sq += __shfl_xor(sq, o);
  }
  __shared__ __align__(16) float rs[4], rq[4];
  const int wave = tid >> 6, lane = tid & 63;
  if (lane == 0) {
    rs[wave] = s;
    rq[wave] = sq;
  }
  __syncthreads();
  const float S1 = rs[0] + rs[1] + rs[2] + rs[3];
  const float S2 = rq[0] + rq[1] + rq[2] + rq[3];
  const float mean = S1 * (1.f / 1024.f);
  const float var = fmaxf(0.f, (S2 - 1024.f * mean * mean) * (1.f / 1023.f));
  const float rstd = 1.f / (sqrtf(var) + 1e-6f);
  const float alpha = ap[0], beta = cp[0];
#pragma unroll
  for (int i = 0; i < 4; i++)
    out[base + tid + i * 256] = f2b(alpha * (v[i] - mean) * rstd + beta);
}

// ---------------------------------------------------------------------------
// 256x256 8-wave deep-pipelined bf16 GEMM (8-phase-template-derived):
// BK=64, 2x4 wave grid (128x64 per wave), 128 KiB dbuf LDS, XOR-swizzled
// chunks (ch ^= row&7 at 16B granule; inverse swizzle on the *global* source
// so global_load_lds dest stays linear), counted vmcnt(8) at tile boundaries
// (next tile's loads stay in flight across barriers), setprio around MFMA.
// EPI 2: bf16 out = relu(acc + bias0)
// EPI 4: QKV fused scatter (bands -> out/outK/outV-transposed)
// Requires M%256==0, N%256==0, K%64==0, gridDim=(N/256, M/256), 512 thr.
// ---------------------------------------------------------------------------
__device__ __forceinline__ void stage_tile(const unsigned short* pA0,
                                           const unsigned short* pB0,
                                           unsigned short* ldsbuf, int wave,
                                           size_t K64, int koff) {
#pragma unroll
  for (int j = 0; j < 4; j++)
    gload_lds16(pA0 + j * K64 + koff, ldsbuf + j * 4096 + wave * 512);
#pragma unroll
  for (int j = 0; j < 4; j++)
    gload_lds16(pB0 + j * K64 + koff, ldsbuf + 16384 + j * 4096 + wave * 512);
}

template <int EPI>
__global__ __launch_bounds__(512, 2) void gemm256(
    const unsigned short* __restrict__ A, const unsigned short* __restrict__ W,
    const float* __restrict__ bias0, const float* __restrict__ bias1,
    const float* __restrict__ bias2, void* __restrict__ out,
    unsigned short* __restrict__ outK, unsigned short* __restrict__ outV,
    int M, int N, int K) {
  __shared__ __align__(16) unsigned short lds[2 * 32768];  // 128 KiB
  const int tid = threadIdx.x;
  const int lane = tid & 63, wave = tid >> 6;
  const int quad = lane >> 4, l16 = lane & 15;

  // XCD-aware bijective swizzle (only when grid % 8 == 0)
  const int nbx = gridDim.x;
  const int nwg = nbx * gridDim.y;
  int wg = blockIdx.y * nbx + blockIdx.x;
  if (!(nwg & 7)) wg = (wg & 7) * (nwg >> 3) + (wg >> 3);
  const int bx = wg % nbx, by = wg / nbx;
  const int m0 = by * 256, n0 = bx * 256;
  const int wm = wave >> 2, wn = wave & 3;  // 2(M) x 4(N) wave grid

  // staging: thread covers row (wave*8 + lane>>3) of each 64-row group,
  // 16B chunk (lane&7); global source pre-swizzled: ch = (lane&7)^(lane>>3)
  const int srow = wave * 8 + (lane >> 3);
  const int scol = ((lane & 7) ^ (lane >> 3)) * 8;
  const size_t K64 = (size_t)K * 64;
  const unsigned short* pA0 = A + (size_t)(m0 + srow) * K + scol;
  const unsigned short* pB0 = W + (size_t)(n0 + srow) * K + scol;

  // fragment read addressing (read-side swizzle: same involution, r&7 = l16&7)
  const int xr = l16 & 7;
  const int aoff0 = ((0 + quad) ^ xr) * 8;  // kh=0 chunk
  const int aoff1 = ((4 + quad) ^ xr) * 8;  // kh=1 chunk
  const int arow = wm * 128 + l16;
  const int brow = wn * 64 + l16;

  f32x4 acc[8][4];
#pragma unroll
  for (int i = 0; i < 8; i++)
#pragma unroll
    for (int j = 0; j < 4; j++) acc[i][j] = {0.f, 0.f, 0.f, 0.f};

  const int nkt = K >> 6;
  // prologue: tiles 0,1 staged; wait tile0 (tile1's 8 stay in flight)
  stage_tile(pA0, pB0, &lds[0], wave, K64, 0);
  stage_tile(pA0, pB0, &lds[32768], wave, K64, 64);
  VMC8;
  SB0;
  BAR;

  short8 af[4][2], bf[4][2];
  for (int t = 0; t < nkt; ++t) {
    const int p = t & 1;
    const unsigned short* Ab = &lds[p * 32768];
    const unsigned short* Bb = Ab + 16384;

    // ---- ph0: read all B frags + A0 frags (16 ds_read_b128) ----
#pragma unroll
    for (int nt = 0; nt < 4; nt++) {
      bf[nt][0] = *(const short8*)&Bb[(brow + nt * 16) * 64 + aoff0];
      bf[nt][1] = *(const short8*)&Bb[(brow + nt * 16) * 64 + aoff1];
    }
#pragma unroll
    for (int mt = 0; mt < 4; mt++) {
      af[mt][0] = *(const short8*)&Ab[(arow + mt * 16) * 64 + aoff0];
      af[mt][1] = *(const short8*)&Ab[(arow + mt * 16) * 64 + aoff1];
    }
    BAR;
    LGK0;
    SB0;
    PRIO1;
#pragma unroll
    for (int mt = 0; mt < 4; mt++)
#pragma unroll
      for (int nt = 0; nt < 2; nt++) {
        acc[mt][nt] = mfma16(af[mt][0], bf[nt][0], acc[mt][nt]);
        acc[mt][nt] = mfma16(af[mt][1], bf[nt][1], acc[mt][nt]);
      }
    PRIO0;
    BAR;
    // ---- ph1: A0 x B-hi (register-only) ----
    PRIO1;
#pragma unroll
    for (int mt = 0; mt < 4; mt++)
#pragma unroll
      for (int nt = 2; nt < 4; nt++) {
        acc[mt][nt] = mfma16(af[mt][0], bf[nt][0], acc[mt][nt]);
        acc[mt][nt] = mfma16(af[mt][1], bf[nt][1], acc[mt][nt]);
      }
    PRIO0;
    BAR;
    // ---- ph2: read A1 frags; then (all cur reads done) stage t+2 -> cur ----
#pragma unroll
    for (int i = 0; i < 4; i++) {
      af[i][0] = *(const short8*)&Ab[(arow + 64 + i * 16) * 64 + aoff0];
      af[i][1] = *(const short8*)&Ab[(arow + 64 + i * 16) * 64 + aoff1];
    }
    LGK0;  // this wave's reads of cur complete before barrier
    SB0;
    BAR;   // => ALL waves' reads of cur complete; safe to overwrite
    if (t + 2 < nkt) stage_tile(pA0, pB0, &lds[p * 32768], wave, K64, (t + 2) * 64);
    PRIO1;
#pragma unroll
    for (int i = 0; i < 4; i++)
#pragma unroll
      for (int nt = 0; nt < 2; nt++) {
        acc[4 + i][nt] = mfma16(af[i][0], bf[nt][0], acc[4 + i][nt]);
        acc[4 + i][nt] = mfma16(af[i][1], bf[nt][1], acc[4 + i][nt]);
      }
    PRIO0;
    BAR;
    // ---- ph3: A1 x B-hi; counted vmcnt -> next tile landed, t+2 in flight ----
    PRIO1;
#pragma unroll
    for (int i = 0; i < 4; i++)
#pragma unroll
      for (int nt = 2; nt < 4; nt++) {
        acc[4 + i][nt] = mfma16(af[i][0], bf[nt][0], acc[4 + i][nt]);
        acc[4 + i][nt] = mfma16(af[i][1], bf[nt][1], acc[4 + i][nt]);
      }
    PRIO0;
    if (t + 2 < nkt) {
      VMC8;
    } else if (t + 1 < nkt) {
      VMC0;
    }
    SB0;
    BAR;
  }

  // ---- epilogue ----
  if (EPI == 4) {
    const int band = (n0 + wn * 64) >> 10;
    const float* bp = band == 0 ? bias0 : (band == 1 ? bias1 : bias2);
#pragma unroll
    for (int nt = 0; nt < 4; nt++) {
      const int col = n0 + wn * 64 + nt * 16 + l16;
      const int cl = col & 1023;
      const float bv = bp[cl];
#pragma unroll
      for (int mt = 0; mt < 8; mt++) {
#pragma unroll
        for (int r = 0; r < 4; r++) {
          const int row = m0 + wm * 128 + mt * 16 + quad * 4 + r;
          const float v = acc[mt][nt][r] + bv;
          if (band == 0)
            ((unsigned short*)out)[(size_t)row * 1024 + cl] = f2b(v);
          else if (band == 1)
            outK[(size_t)row * 1024 + cl] = f2b(v);
          else
            outV[((size_t)((row >> 11) * 1024 + cl)) * 2048 + (row & 2047)] = f2b(v);
        }
      }
    }
  } else {  // EPI == 2: relu -> bf16
#pragma unroll
    for (int nt = 0; nt < 4; nt++) {
      const int col = n0 + wn * 64 + nt * 16 + l16;
      const float bv = bias0[col];
#pragma unroll
      for (int mt = 0; mt < 8; mt++)
#pragma unroll
        for (int r = 0; r < 4; r++) {
          const int row = m0 + wm * 128 + mt * 16 + quad * 4 + r;
          ((unsigned short*)out)[(size_t)row * (size_t)N + col] =
              f2b(fmaxf(acc[mt][nt][r] + bv, 0.f));
        }
    }
  }
}

// ---------------------------------------------------------------------------
// Pure-bf16 GEMM (m97 structure): kept for N=1024 GEMMs (AO, FFN2) where the
// 256^2 kernel's grid would be 128 blocks (half the CUs idle).
// ---------------------------------------------------------------------------
template <int EPI>
__global__ __launch_bounds__(256) void gemm_bb(
    const unsigned short* __restrict__ A, const unsigned short* __restrict__ W,
    const float* __restrict__ bias0, const float* __restrict__ bias1,
    const float* __restrict__ bias2, const float* __restrict__ resid,
    void* __restrict__ out, unsigned short* __restrict__ outK,
    unsigned short* __restrict__ outV, int M, int N, int K, int ldw) {
  __shared__ __align__(16) unsigned short As[128 * 32];
  __shared__ __align__(16) unsigned short Bs[128 * 32];
  const int tid = threadIdx.x;
  const int lane = tid & 63, wave = tid >> 6;
  const int quad = lane >> 4, l16 = lane & 15;
  const int m0 = blockIdx.y * 128, n0 = blockIdx.x * 128;
  const int wm = (wave >> 1) * 64, wn = (wave & 1) * 64;

  f32x4 acc[4][4];
#pragma unroll
  for (int i = 0; i < 4; i++)
#pragma unroll
    for (int j = 0; j < 4; j++) acc[i][j] = {0.f, 0.f, 0.f, 0.f};

  const int rA = tid >> 2;       // 0..63 row within half-tile
  const int kc = (tid & 3) * 8;  // 8-elem (16B) chunk

  for (int k0 = 0; k0 < K; k0 += 32) {
    __syncthreads();
#pragma unroll
    for (int i = 0; i < 2; i++) {
      const int row = i * 64 + rA;
      gload_lds16(&A[(size_t)(m0 + row) * K + k0 + kc], &As[(i * 256 + wave * 64) * 8]);
      gload_lds16(&W[(size_t)(n0 + row) * ldw + k0 + kc], &Bs[(i * 256 + wave * 64) * 8]);
    }
    __syncthreads();
    short8 af[4], bf[4];
#pragma unroll
    for (int t = 0; t < 4; t++) {
      af[t] = *(const short8*)&As[(wm + t * 16 + l16) * 32 + quad * 8];
      bf[t] = *(const short8*)&Bs[(wn + t * 16 + l16) * 32 + quad * 8];
    }
#pragma unroll
    for (int mt = 0; mt < 4; mt++)
#pragma unroll
      for (int nt = 0; nt < 4; nt++) acc[mt][nt] = mfma16(af[mt], bf[nt], acc[mt][nt]);
  }

  if (EPI == 4) {
    const int band = (n0 + wn) >> 10;
    const float* bp = band == 0 ? bias0 : (band == 1 ? bias1 : bias2);
#pragma unroll
    for (int nt = 0; nt < 4; nt++) {
      const int col = n0 + wn + nt * 16 + l16;
      const int cl = col & 1023;
      const float bv = bp[cl];
#pragma unroll
      for (int mt = 0; mt < 4; mt++) {
#pragma unroll
        for (int r = 0; r < 4; r++) {
          const int row = m0 + wm + mt * 16 + quad * 4 + r;
          const float v = acc[mt][nt][r] + bv;
          if (band == 0)
            ((unsigned short*)out)[(size_t)row * 1024 + cl] = f2b(v);
          else if (band == 1)
            outK[(size_t)row * 1024 + cl] = f2b(v);
          else
            outV[((size_t)((row >> 11) * 1024 + cl)) * 2048 + (row & 2047)] = f2b(v);
        }
      }
    }
  } else {
#pragma unroll
    for (int nt = 0; nt < 4; nt++) {
      const int col = n0 + wn + nt * 16 + l16;
      const float bv = (EPI == 3) ? 0.f : bias0[col];
#pragma unroll
      for (int mt = 0; mt < 4; mt++) {
#pragma unroll
        for (int r = 0; r < 4; r++) {
          const int row = m0 + wm + mt * 16 + quad * 4 + r;
          const size_t idx = (size_t)row * N + col;
          float v = acc[mt][nt][r] + bv;
          if (EPI == 2) {
            v = fmaxf(v, 0.f);
            ((unsigned short*)out)[idx] = f2b(v);
          } else {
            v += resid[idx];
            ((float*)out)[idx] = v;
          }
        }
      }
    }
  }
}

// ---------------------------------------------------------------------------
// Flash attention, S^T orientation + fixed-max softmax. (+ T5 setprio)
// ---------------------------------------------------------------------------
__global__ __launch_bounds__(256) void attn_kernel(unsigned short* __restrict__ Q,
                                                   const unsigned short* __restrict__ Kb,
                                                   const unsigned short* __restrict__ VT,
                                                   const int* __restrict__ mask) {
  constexpr int PAD = 72;
  __shared__ __align__(16) unsigned short Ks[64 * PAD];
  __shared__ __align__(16) unsigned short VTs[64 * PAD];
  __shared__ __align__(16) unsigned short Pb[4][16 * PAD];

  const int tid = threadIdx.x, lane = tid & 63, wave = tid >> 6;
  const int quad = lane >> 4, l16 = lane & 15;
  const int q0 = blockIdx.x * 64;
  const int b = blockIdx.y >> 4, h = blockIdx.y & 15;

  short8 qf0, qf1;
  {
    const int qr = q0 + wave * 16 + l16;
    const unsigned short* qp = &Q[((size_t)(b * S) + qr) * D + h * 64 + quad * 8];
    qf0 = *(const short8*)qp;
    qf1 = *(const short8*)(qp + 32);
  }

  float l_acc = 0.f;  // partial sum for q = l16
  f32x4 o_acc[4];
#pragma unroll
  for (int t = 0; t < 4; t++) o_acc[t] = {0.f, 0.f, 0.f, 0.f};

  const int rT = tid >> 3;
  const int cT = (tid & 7) * 8;

  for (int kt = 0; kt < S / 64; kt++) {
    const int k0 = kt * 64;
    ushort8 kv[2], vv[2];
#pragma unroll
    for (int i = 0; i < 2; i++) {
      const int r = i * 32 + rT;
      kv[i] = *(const ushort8*)&Kb[((size_t)(b * S) + k0 + r) * D + h * 64 + cT];
      vv[i] = *(const ushort8*)&VT[((size_t)(blockIdx.y * 64 + r)) * S + k0 + cT];
    }
    __syncthreads();
#pragma unroll
    for (int i = 0; i < 2; i++) {
      const int r = i * 32 + rT;
      *(ushort8*)&Ks[r * PAD + cT] = kv[i];
      *(ushort8*)&VTs[r * PAD + cT] = vv[i];
    }
    __syncthreads();

    // S^T = K Q^T
    f32x4 sc[4];
#pragma unroll
    for (int nt = 0; nt < 4; nt++) sc[nt] = {0.f, 0.f, 0.f, 0.f};
    PRIO1;
#pragma unroll
    for (int nt = 0; nt < 4; nt++) {
      short8 kf0 = *(const short8*)&Ks[(nt * 16 + l16) * PAD + quad * 8];
      short8 kf1 = *(const short8*)&Ks[(nt * 16 + l16) * PAD + 32 + quad * 8];
      sc[nt] = mfma16(kf0, qf0, sc[nt]);
      sc[nt] = mfma16(kf1, qf1, sc[nt]);
    }
    PRIO0;

    // p = exp(s*0.125 - 12) (masked: -42); pack 4 keys -> one b64 write
#pragma unroll
    for (int nt = 0; nt < 4; nt++) {
      const int4 mv = *(const int4*)&mask[b * S + k0 + nt * 16 + quad * 4];
      ushort4v pk;
      {
        const float p0 = __expf(fmaf(sc[nt][0], 0.125f, mv.x ? -12.f : -42.f));
        const float p1 = __expf(fmaf(sc[nt][1], 0.125f, mv.y ? -12.f : -42.f));
        const float p2 = __expf(fmaf(sc[nt][2], 0.125f, mv.z ? -12.f : -42.f));
        const float p3 = __expf(fmaf(sc[nt][3], 0.125f, mv.w ? -12.f : -42.f));
        l_acc += p0 + p1 + p2 + p3;
        pk[0] = f2b(p0);
        pk[1] = f2b(p1);
        pk[2] = f2b(p2);
        pk[3] = f2b(p3);
      }
      *(ushort4v*)&Pb[wave][l16 * PAD + nt * 16 + quad * 4] = pk;
    }

    // P @ V
    short8 pf0 = *(const short8*)&Pb[wave][l16 * PAD + quad * 8];
    short8 pf1 = *(const short8*)&Pb[wave][l16 * PAD + 32 + quad * 8];
    PRIO1;
#pragma unroll
    for (int nt = 0; nt < 4; nt++) {
      short8 vf0 = *(const short8*)&VTs[(nt * 16 + l16) * PAD + quad * 8];
      short8 vf1 = *(const short8*)&VTs[(nt * 16 + l16) * PAD + 32 + quad * 8];
      o_acc[nt] = mfma16(pf0, vf0, o_acc[nt]);
      o_acc[nt] = mfma16(pf1, vf1, o_acc[nt]);
    }
    PRIO0;
  }

  l_acc += __shfl_xor(l_acc, 16);
  l_acc += __shfl_xor(l_acc, 32);

#pragma unroll
  for (int r = 0; r < 4; r++) {
    const float lr = __shfl(l_acc, quad * 4 + r);
    const float inv = 1.f / lr;
    const int q = q0 + wave * 16 + quad * 4 + r;
#pragma unroll
    for (int nt = 0; nt < 4; nt++) {
      const int dk = nt * 16 + l16;
      Q[((size_t)(b * S) + q) * D + h * 64 + dk] = f2b(o_acc[nt][r] * inv);
    }
  }
}

// ---------------------------------------------------------------------------
// FALLBACK path (ws < 89MB): round-5 kernels
// ---------------------------------------------------------------------------
__global__ __launch_bounds__(256) void stats_kernel(const float* __restrict__ x,
                                                    float2* __restrict__ st) {
  const int row = blockIdx.x, tid = threadIdx.x;
  const size_t base = (size_t)row * D;
  float s = 0.f, sq = 0.f;
#pragma unroll
  for (int i = 0; i < 4; i++) {
    const float v = x[base + tid + i * 256];
    s += v;
    sq += v * v;
  }
#pragma unroll
  for (int o = 32; o > 0; o >>= 1) {
    s += __shfl_xor(s, o);
    sq += __shfl_xor(sq, o);
  }
  __shared__ __align__(16) float rs[4], rq[4];
  const int wave = tid >> 6, lane = tid & 63;
  if (lane == 0) {
    rs[wave] = s;
    rq[wave] = sq;
  }
  __syncthreads();
  if (tid == 0) {
    const float S1 = rs[0] + rs[1] + rs[2] + rs[3];
    const float S2 = rq[0] + rq[1] + rq[2] + rq[3];
    const float mean = S1 * (1.f / 1024.f);
    const float var = fmaxf(0.f, (S2 - 1024.f * mean * mean) * (1.f / 1023.f));
    const float rstd = 1.f / (sqrtf(var) + 1e-6f);
    st[row] = make_float2(mean, rstd);
  }
}

template <int EPI, int NORM, int AF32, int OUTF32>
__global__ __launch_bounds__(256) void gemm_bt(
    const void* __restrict__ Ap, const float* __restrict__ W,
    const float* __restrict__ bias, const float* __restrict__ resid,
    void* __restrict__ outp, const float2* __restrict__ stats,
    const float* __restrict__ alpha_p, const float* __restrict__ beta_p,
    int M, int N, int K, int ldw) {
  __shared__ __align__(16) unsigned short As[128 * 32];
  __shared__ __align__(16) unsigned short Bs[128 * 32];
  const int tid = threadIdx.x;
  const int lane = tid & 63, wave = tid >> 6;
  const int quad = lane >> 4, l16 = lane & 15;
  const int m0 = blockIdx.y * 128, n0 = blockIdx.x * 128;
  const int wm = (wave >> 1) * 64, wn = (wave & 1) * 64;

  float alpha = 0.f, beta = 0.f;
  if (NORM) {
    alpha = alpha_p[0];
    beta = beta_p[0];
  }

  f32x4 acc[4][4];
#pragma unroll
  for (int i = 0; i < 4; i++)
#pragma unroll
    for (int j = 0; j < 4; j++) acc[i][j] = {0.f, 0.f, 0.f, 0.f};

  const int rA = tid >> 2;
  const int kc = (tid & 3) * 8;

  for (int k0 = 0; k0 < K; k0 += 32) {
    ushort8 av[2], bv8[2];
#pragma unroll
    for (int i = 0; i < 2; i++) {
      const int row = i * 64 + rA;
      if (AF32) {
        const float* ap = (const float*)Ap + (size_t)(m0 + row) * K + k0 + kc;
        f32x4 a0 = *(const f32x4*)ap;
        f32x4 a1 = *(const f32x4*)(ap + 4);
        if (NORM) {
          const float2 st = stats[m0 + row];
#pragma unroll
          for (int j = 0; j < 4; j++) {
            a0[j] = alpha * (a0[j] - st.x) * st.y + beta;
            a1[j] = alpha * (a1[j] - st.x) * st.y + beta;
          }
        }
#pragma unroll
        for (int j = 0; j < 4; j++) {
          av[i][j] = f2b(a0[j]);
          av[i][j + 4] = f2b(a1[j]);
        }
      } else {
        av[i] = *(const ushort8*)((const unsigned short*)Ap +
                                  (size_t)(m0 + row) * K + k0 + kc);
      }
      const float* wp = W + (size_t)(n0 + row) * ldw + k0 + kc;
      f32x4 w0 = *(const f32x4*)wp;
      f32x4 w1 = *(const f32x4*)(wp + 4);
#pragma unroll
      for (int j = 0; j < 4; j++) {
        bv8[i][j] = f2b(w0[j]);
        bv8[i][j + 4] = f2b(w1[j]);
      }
    }
    __syncthreads();
#pragma unroll
    for (int i = 0; i < 2; i++) {
      const int row = i * 64 + rA;
      *(ushort8*)&As[row * 32 + kc] = av[i];
      *(ushort8*)&Bs[row * 32 + kc] = bv8[i];
    }
    __syncthreads();
    short8 af[4], bf[4];
#pragma unroll
    for (int t = 0; t < 4; t++) {
      af[t] = *(const short8*)&As[(wm + t * 16 + l16) * 32 + quad * 8];
      bf[t] = *(const short8*)&Bs[(wn + t * 16 + l16) * 32 + quad * 8];
    }
#pragma unroll
    for (int mt = 0; mt < 4; mt++)
#pragma unroll
      for (int nt = 0; nt < 4; nt++) acc[mt][nt] = mfma16(af[mt], bf[nt], acc[mt][nt]);
  }

#pragma unroll
  for (int nt = 0; nt < 4; nt++) {
    const int col = n0 + wn + nt * 16 + l16;
    const float bv = (EPI == 3) ? 0.f : bias[col];
#pragma unroll
    for (int mt = 0; mt < 4; mt++) {
#pragma unroll
      for (int r = 0; r < 4; r++) {
        const int row = m0 + wm + mt * 16 + quad * 4 + r;
        float v = acc[mt][nt][r] + bv;
        if (EPI == 2) v = fmaxf(v, 0.f);
        if (EPI == 4) {
          const size_t vtidx =
              ((size_t)((row >> 11) * 1024 + col)) * 2048 + (row & 2047);
          ((unsigned short*)outp)[vtidx] = f2b(v);
        } else {
          const size_t idx = (size_t)row * N + col;
          if (EPI == 1 || EPI == 3) v += resid[idx];
          if (OUTF32)
            ((float*)outp)[idx] = v;
          else
            ((unsigned short*)outp)[idx] = f2b(v);
        }
      }
    }
  }
}

// ---------------------------------------------------------------------------
extern "C" void kernel_launch(void* const* d_in, const int* in_sizes, int n_in,
                              void* d_out, int out_size, void* d_ws, size_t ws_size,
                              hipStream_t stream) {
  (void)in_sizes; (void)n_in; (void)out_size;
  const float* x  = (const float*)d_in[0];
  const int* mask = (const int*)d_in[1];
  const float* wq = (const float*)d_in[2];
  const float* bq = (const float*)d_in[3];
  const float* wk = (const float*)d_in[4];
  const float* bk = (const float*)d_in[5];
  const float* wv = (const float*)d_in[6];
  const float* bv = (const float*)d_in[7];
  const float* wo = (const float*)d_in[8];
  const float* bo = (const float*)d_in[9];
  const float* w1 = (const float*)d_in[10];
  const float* b1 = (const float*)d_in[11];
  const float* w2 = (const float*)d_in[12];
  const float* b2 = (const float*)d_in[13];
  const float* a1 = (const float*)d_in[14];
  const float* c1 = (const float*)d_in[15];
  const float* a2 = (const float*)d_in[16];
  const float* c2 = (const float*)d_in[17];

  char* ws = (char*)d_ws;
  const size_t MB = 1 << 20;
  const int M = B * S;  // 8192
  dim3 blk(256);
  dim3 blk512(512);
  dim3 gAttn(S / 64, B * H);  // (32, 64)

  if (ws_size >= 89 * MB) {
    const int tier3 = (ws_size >= 152 * MB);
    const int tier2 = (ws_size >= 121 * MB);
    unsigned short* wqkv_b = (unsigned short*)(ws + 0);        // 6 MB
    unsigned short* wo_b   = (unsigned short*)(ws + 6 * MB);   // 2 MB
    unsigned short* w1_b   = (unsigned short*)(ws + 8 * MB);   // 8 MB
    unsigned short* w2_b   = (unsigned short*)(ws + 16 * MB);  // 8 MB
    unsigned short* ln1x   = (unsigned short*)(ws + 25 * MB);  // 16 MB
    unsigned short* q      = (unsigned short*)(ws + 41 * MB);  // 16 MB
    unsigned short* kk     = (unsigned short*)(ws + 57 * MB);  // 16 MB
    unsigned short* vt     = (unsigned short*)(ws + 73 * MB);  // 16 MB
    float*          hbuf   = (float*)(ws + 57 * MB);           // 32 MB (over kk+vt)
    unsigned short* ln2x   = (unsigned short*)(ws + 25 * MB);  // over ln1x
    unsigned short* ffn1q  = (unsigned short*)(ws + 41 * MB);  // over q (tier1)
    unsigned short* ffn1h  = (unsigned short*)(ws + 89 * MB);  // 32 MB (tier2)
    unsigned short* ffn1f  = (unsigned short*)(ws + 89 * MB);  // 64 MB (tier3)
    float* outb = (float*)d_out;

    // weights -> bf16, one batched dispatch
    CvtArgs ca;
    ca.s[0] = wq; ca.d[0] = wqkv_b;            ca.n[0] = 1048576;
    ca.s[1] = wk; ca.d[1] = wqkv_b + 1048576;  ca.n[1] = 1048576;
    ca.s[2] = wv; ca.d[2] = wqkv_b + 2097152;  ca.n[2] = 1048576;
    ca.s[3] = wo; ca.d[3] = wo_b;              ca.n[3] = 1048576;
    ca.s[4] = w1; ca.d[4] = w1_b;              ca.n[4] = 4194304;
    ca.s[5] = w2; ca.d[5] = w2_b;              ca.n[5] = 4194304;
    convert6<<<dim3(4096, 6), blk, 0, stream>>>(ca);

    ln_fused<<<M, blk, 0, stream>>>(x, a1, c1, ln1x);
    // QKV: 256^2 8-wave deep-pipelined kernel, grid (3072/256, 8192/256)
    gemm256<4><<<dim3(12, 32), blk512, 0, stream>>>(ln1x, wqkv_b, bq, bk, bv,
                                                    q, kk, vt, M, 3072, D);
    attn_kernel<<<gAttn, blk, 0, stream>>>(q, kk, vt, mask);
    gemm_bb<1><<<dim3(8, 64), blk, 0, stream>>>(q, wo_b, bo, nullptr, nullptr, x,
                                                hbuf, nullptr, nullptr, M, D, D, D);
    ln_fused<<<M, blk, 0, stream>>>(hbuf, a2, c2, ln2x);

    if (tier3) {
      // FFN1: 256^2 kernel, grid (4096/256, 8192/256) = 512 blocks (2 rounds)
      gemm256<2><<<dim3(16, 32), blk512, 0, stream>>>(ln2x, w1_b, b1, nullptr,
                                                      nullptr, ffn1f, nullptr,
                                                      nullptr, M, DFF, D);
      gemm_bb<1><<<dim3(8, 64), blk, 0, stream>>>(ffn1f, w2_b, b2, nullptr, nullptr,
                                                  hbuf, outb, nullptr, nullptr,
                                                  M, D, DFF, DFF);
    } else if (tier2) {
      gemm_bb<2><<<dim3(16, 64), blk, 0, stream>>>(ln2x, w1_b, b1, nullptr, nullptr,
                                                   nullptr, ffn1h, nullptr, nullptr,
                                                   M, 2048, D, D);
      gemm_bb<1><<<dim3(8, 64), blk, 0, stream>>>(ffn1h, w2_b, b2, nullptr, nullptr,
                                                  hbuf, outb, nullptr, nullptr,
                                                  M, D, 2048, DFF);
      gemm_bb<2><<<dim3(16, 64), blk, 0, stream>>>(ln2x, w1_b + (size_t)2048 * D,
                                                   b1 + 2048, nullptr, nullptr, nullptr,
                                                   ffn1h, nullptr, nullptr, M, 2048, D, D);
      gemm_bb<3><<<dim3(8, 64), blk, 0, stream>>>(ffn1h, w2_b + 2048, nullptr, nullptr,
                                                  nullptr, outb, outb, nullptr, nullptr,
                                                  M, D, 2048, DFF);
    } else {
      for (int i = 0; i < 4; i++) {
        gemm_bb<2><<<dim3(8, 64), blk, 0, stream>>>(ln2x, w1_b + (size_t)i * 1024 * D,
                                                    b1 + i * 1024, nullptr, nullptr,
                                                    nullptr, ffn1q, nullptr, nullptr,
                                                    M, 1024, D, D);
        if (i == 0)
          gemm_bb<1><<<dim3(8, 64), blk, 0, stream>>>(ffn1q, w2_b + i * 1024, b2, nullptr,
                                                      nullptr, hbuf, outb, nullptr, nullptr,
                                                      M, D, 1024, DFF);
        else
          gemm_bb<3><<<dim3(8, 64), blk, 0, stream>>>(ffn1q, w2_b + i * 1024, nullptr,
                                                      nullptr, nullptr, outb, outb, nullptr,
                                                      nullptr, M, D, 1024, DFF);
      }
    }
  } else {
    // fallback (round-5 structure, 49 MB peak)
    float2* stats1 = (float2*)(ws + 0);
    float2* stats2 = (float2*)(ws + 128 * 1024);
    unsigned short* q    = (unsigned short*)(ws + 1 * MB);
    unsigned short* kk   = (unsigned short*)(ws + 17 * MB);
    unsigned short* vt   = (unsigned short*)(ws + 33 * MB);
    float*          hbuf = (float*)(ws + 17 * MB);
    unsigned short* ffn1 = (unsigned short*)(ws + 1 * MB);
    float* outb = (float*)d_out;
    dim3 gD(D / 128, M / 128);

    stats_kernel<<<M, blk, 0, stream>>>(x, stats1);
    gemm_bt<0, 1, 1, 0><<<gD, blk, 0, stream>>>(x, wq, bq, nullptr, q, stats1, a1, c1, M, D, D, D);
    gemm_bt<0, 1, 1, 0><<<gD, blk, 0, stream>>>(x, wk, bk, nullptr, kk, stats1, a1, c1, M, D, D, D);
    gemm_bt<4, 1, 1, 0><<<gD, blk, 0, stream>>>(x, wv, bv, nullptr, vt, stats1, a1, c1, M, D, D, D);
    attn_kernel<<<gAttn, blk, 0, stream>>>(q, kk, vt, mask);
    gemm_bt<1, 0, 0, 1><<<gD, blk, 0, stream>>>(q, wo, bo, x, hbuf, nullptr, nullptr, nullptr, M, D, D, D);
    stats_kernel<<<M, blk, 0, stream>>>(hbuf, stats2);
    for (int i = 0; i < 4; i++) {
      gemm_bt<2, 1, 1, 0><<<gD, blk, 0, stream>>>(hbuf, w1 + (size_t)i * 1024 * D,
                                                  b1 + i * 1024, nullptr, ffn1, stats2,
                                                  a2, c2, M, 1024, D, D);
      if (i == 0)
        gemm_bt<1, 0, 0, 1><<<gD, blk, 0, stream>>>(ffn1, w2 + i * 1024, b2, hbuf, outb,
                                                    nullptr, nullptr, nullptr, M, D, 1024, DFF);
      else
        gemm_bt<3, 0, 0, 1><<<gD, blk, 0, stream>>>(ffn1, w2 + i * 1024, nullptr, outb, outb,
                                                    nullptr, nullptr, nullptr, M, D, 1024, DFF);
    }
  }
}